// Round 3
// baseline (11194.456 us; speedup 1.0000x reference)
//
#include <hip/hip_runtime.h>
#include <math.h>

// UKF, one block/trajectory, 512 threads. R4: attack the LDS pipe (R3 was
// ~11K ds-inst/step ~= 50K cy/step on the shared per-CU LDS unit).
//  - PS 65->68: every P access is float4 (panel, trailing, FL, T).
//  - chol: panel-32 in-register on wave0 (2 panels, 3 barriers, fma order
//    bitwise-identical to panel-16); zero-filled upper-L at store -> no
//    triangular predicates anywhere; role-swapped rank-32 trailing (lane=col,
//    f4 uniform panel rows): ~2100 -> ~300 ds-inst.
//  - sigma rows pre-centered once (+1 barrier) -> Pn = pure f4 fma, 4x4 tiles
//    on 4 waves (2048 -> 1024 ds); innovation overlapped on wave4.
//  - Pxz/Pz replaced by T = H@Pn (Pn symmetric => Pxz = T^T, Pz = T@H^T + R):
//    2560 -> 384 ds-inst; K and M read T rows as float4.
//  - M + P_new + outP fused: tile computes (P+Q)-Msym, writes scaled P (and
//    mirror) + raw outP directly; Mb buffer, P+=Q phase, writeback phase gone.
//  Barriers 17 -> 13/step. LDS 64,640 B.
// R5 == R4 resubmitted: prior round failed on container acquisition (infra),
// kernel re-audited (LDS 64,640 < 65,536; all global indices in range).

#define NTRAJ 128
#define TSTEPS 250
#define NS 64
#define NO 32
#define PS 68    // P row stride (mult of 4 -> float4 rows)
#define SFS 68   // sigma buffer row stride
#define HTS 36   // H^T row stride (row j holds H[:,j])
#define TS 68    // T = H@Pn row stride (row m holds (H Pn)[m,:] = Pxz[:,m])
#define GJS 68   // Pz stride
#define PZS 36   // Pzinv col-major stride
#define KS 36    // K row stride
#define BLK 512

#define DTc 0.02f
#define W_C (0.5f/63.0f)
#define WM0 (-1.0f/63.0f)
#define WC0 (2.0f - 1.0f/63.0f)
#define DEPS 6.3e-7f

__device__ __forceinline__ float tanh_fast(float x) {
  float e = __expf(2.0f * x);
  return 1.0f - 2.0f / (e + 1.0f);
}

__global__ __launch_bounds__(BLK)
void ukf_main(const float* __restrict__ Xg, const float* __restrict__ Yg,
              const float* __restrict__ Fg, const float* __restrict__ Hg,
              const float* __restrict__ Qg, const float* __restrict__ Rg,
              float* __restrict__ outX, float* __restrict__ outP,
              float* __restrict__ wsPart)
{
  __shared__ __align__(16) float P[NS*PS];      // 4352: P / L / Pn / P_new
  __shared__ __align__(16) float sfb[128*SFS];  // 8704: F^T+FL+sigma; overlays
  __shared__ __align__(16) float sHT[NS*HTS];   // 2304: H^T persistent
  __shared__ __align__(16) float sPart[8*NS];   // 512
  __shared__ __align__(16) float sx[NS];
  __shared__ __align__(16) float sxp[NS];
  __shared__ __align__(16) float sFx[NS];
  __shared__ __align__(16) float s0[NS];
  __shared__ __align__(16) float sinn[NO];

  // overlays on sfb, live only after sigma rows are consumed (post-Pn):
  float* Tb  = sfb;          // [0,    2176): 32 x TS   (T = H@Pn)
  float* Pzb = sfb + 2176;   // [2176, 4352): 32 x GJS  (Pz)
  float* Pzi = sfb + 4352;   // [4352, 5504): 32 x PZS  (Pzinv col-major)
  float* Km  = sfb + 5504;   // [5504, 7808): 64 x KS   (K)

  const int tid  = threadIdx.x;
  const int lane = tid & 63;
  const int grp  = tid >> 6;
  const int traj = blockIdx.x;

  // ---- one-time init: P pre-scaled = 63*(1e-5 + 1e-8) on diag; stage H^T
  for (int o = tid; o < NS*NS; o += BLK) {
    int i = o >> 6, j = o & 63;
    P[i*PS + j] = (i == j) ? (63e-5f + DEPS) : 0.f;
  }
  for (int o = tid; o < NO*NS; o += BLK) {
    int m = o >> 6, j = o & 63;
    sHT[j*HTS + m] = Hg[o];
  }
  if (tid < NS) sx[tid] = 0.f;
  float errAcc = 0.f;
  __syncthreads();

  for (int t = 0; t < TSTEPS; ++t) {
    const size_t sbase = (size_t)traj*TSTEPS + t;

    // ================= Cholesky: panel-32 x2, role-swapped trailing =======
    for (int pc = 0; pc < NS; pc += 32) {
      if (grp == 0) {
        const int i = lane;
        float pr[32];
        #pragma unroll
        for (int c4 = 0; c4 < 8; ++c4)
          *(float4*)&pr[c4*4] = *(const float4*)&P[i*PS + pc + c4*4];
        #pragma unroll
        for (int jj = 0; jj < 32; ++jj) {
          const int gc = pc + jj;
          float dv  = __shfl(pr[jj], gc);
          float inv = rsqrtf(dv);
          pr[jj] = (i == gc) ? dv * inv : ((i < gc) ? 0.f : pr[jj] * inv);
          #pragma unroll
          for (int kk = jj + 1; kk < 32; ++kk) {
            float ck = __shfl(pr[jj], pc + kk);
            pr[kk] = fmaf(-pr[jj], ck, pr[kk]);
          }
        }
        #pragma unroll
        for (int c4 = 0; c4 < 8; ++c4)
          *(float4*)&P[i*PS + pc + c4*4] = *(const float4*)&pr[c4*4];
      } else if (pc == 0) {
        // waves 1-7: stage FT[j][i] = F[i][j] (hidden under panel0 factor)
        for (int c = tid - 64; c < 1024; c += (BLK - 64)) {
          int i = c >> 4, j0 = (c & 15) << 2;
          float4 fv = *(const float4*)&Fg[i*64 + j0];
          sfb[(j0    )*SFS + i] = fv.x;
          sfb[(j0 + 1)*SFS + i] = fv.y;
          sfb[(j0 + 2)*SFS + i] = fv.z;
          sfb[(j0 + 3)*SFS + i] = fv.w;
        }
      }
      __syncthreads();
      if (pc == 0) {
        // trailing rank-32 on rows/cols 32..63: lane = column, f4 everywhere
        const int k  = 32 + (lane & 31);
        const int ib = 32 + grp*2 + (lane >> 5);
        float Lk[32];
        #pragma unroll
        for (int c4 = 0; c4 < 8; ++c4)
          *(float4*)&Lk[c4*4] = *(const float4*)&P[k*PS + c4*4];
        #pragma unroll
        for (int it = 0; it < 2; ++it) {
          const int i = ib + 16*it;
          float acc = P[i*PS + k];
          #pragma unroll
          for (int c4 = 0; c4 < 8; ++c4) {
            float4 pi = *(const float4*)&P[i*PS + c4*4];  // 2 addr/wave
            acc = fmaf(-pi.x, Lk[c4*4    ], acc);
            acc = fmaf(-pi.y, Lk[c4*4 + 1], acc);
            acc = fmaf(-pi.z, Lk[c4*4 + 2], acc);
            acc = fmaf(-pi.w, Lk[c4*4 + 3], acc);
          }
          P[i*PS + k] = acc;
        }
        __syncthreads();
      }
    }

    // ================= FL = F@L (waves 0-3, 4x4 f4 tiles); Fx on wave4 =====
    if (tid < 256) {
      const int c0 = (tid >> 4) << 2;
      const int j0 = (tid & 15) << 2;
      float acc[4][4];
      #pragma unroll
      for (int a = 0; a < 4; ++a)
        #pragma unroll
        for (int b = 0; b < 4; ++b) acc[a][b] = 0.f;
      for (int jj = 0; jj < NS; ++jj) {
        float4 fv = *(const float4*)&sfb[jj*SFS + j0];  // F[j0..j0+3][jj]
        float4 lv = *(const float4*)&P[jj*PS + c0];     // L[jj][c0..c0+3] (upper=0)
        float fa[4] = {fv.x, fv.y, fv.z, fv.w};
        float lb[4] = {lv.x, lv.y, lv.z, lv.w};
        #pragma unroll
        for (int a = 0; a < 4; ++a)
          #pragma unroll
          for (int b = 0; b < 4; ++b)
            acc[a][b] = fmaf(lb[b], fa[a], acc[a][b]);
      }
      #pragma unroll
      for (int b = 0; b < 4; ++b) {
        float4 w4; w4.x = acc[0][b]; w4.y = acc[1][b]; w4.z = acc[2][b]; w4.w = acc[3][b];
        *(float4*)&sfb[(64 + c0 + b)*SFS + j0] = w4;    // FL[j][c] at row 64+c
      }
    } else if (grp == 4) {
      const int i2 = lane;
      float a2 = 0.f;
      for (int jj = 0; jj < NS; ++jj) a2 = fmaf(sfb[jj*SFS + i2], sx[jj], a2);
      sFx[i2] = a2;
    }
    __syncthreads();

    // ================= sigma points + x_pred partials (all 8 waves) ========
    {
      const int j = lane;
      float psum = 0.f;
      float xv = sx[j], fxv = sFx[j];
      for (int cc = grp; cc < NS; cc += 8) {
        float flv = sfb[(64 + cc)*SFS + j];
        float Lv  = P[j*PS + cc];                       // zero above diag
        float vp = xv + Lv + DTc * tanh_fast(fxv + flv);
        float vm = xv - Lv + DTc * tanh_fast(fxv - flv);
        sfb[cc*SFS + j]        = vp;
        sfb[(64 + cc)*SFS + j] = vm;
        psum += vp + vm;
      }
      sPart[grp*NS + j] = psum;
    }
    if (tid < NS) s0[tid] = sx[tid] + DTc * tanh_fast(sFx[tid]);
    __syncthreads();

    // ================= combine -> x_pred, center d0 ========================
    if (tid < NS) {
      float s = sPart[tid]        + sPart[NS+tid]   + sPart[2*NS+tid] + sPart[3*NS+tid]
              + sPart[4*NS+tid]   + sPart[5*NS+tid] + sPart[6*NS+tid] + sPart[7*NS+tid];
      float xp = fmaf(W_C, s, WM0 * s0[tid]);
      sxp[tid] = xp;
      s0[tid] -= xp;
    }
    __syncthreads();

    // ================= center sigma rows in place (f4) =====================
    {
      const int j0 = (tid & 15) << 2;
      float4 xp4 = *(const float4*)&sxp[j0];
      #pragma unroll
      for (int q = 0; q < 4; ++q) {
        const int r = (tid >> 4) + (q << 5);            // 0..127
        float4 v = *(const float4*)&sfb[r*SFS + j0];
        v.x -= xp4.x; v.y -= xp4.y; v.z -= xp4.z; v.w -= xp4.w;
        *(float4*)&sfb[r*SFS + j0] = v;
      }
    }
    __syncthreads();

    // ================= Pn (waves 0-3, 4x4 pure-fma) + innovation (wave4) ===
    if (tid < 256) {
      const int i0 = (tid >> 4) << 2;
      const int j0 = (tid & 15) << 2;
      float acc[4][4];
      #pragma unroll
      for (int a = 0; a < 4; ++a)
        #pragma unroll
        for (int b = 0; b < 4; ++b) acc[a][b] = 0.f;
      #pragma unroll 4
      for (int r = 0; r < 128; ++r) {
        float4 av = *(const float4*)&sfb[r*SFS + i0];
        float4 bv = *(const float4*)&sfb[r*SFS + j0];
        float da[4] = {av.x, av.y, av.z, av.w};
        float db[4] = {bv.x, bv.y, bv.z, bv.w};
        #pragma unroll
        for (int a = 0; a < 4; ++a)
          #pragma unroll
          for (int b = 0; b < 4; ++b)
            acc[a][b] = fmaf(da[a], db[b], acc[a][b]);
      }
      float4 si = *(const float4*)&s0[i0];
      float4 sj = *(const float4*)&s0[j0];
      float s0i[4] = {si.x, si.y, si.z, si.w};
      float s0j[4] = {sj.x, sj.y, sj.z, sj.w};
      #pragma unroll
      for (int a = 0; a < 4; ++a) {
        float d0a = WC0 * s0i[a];
        float4 w4;
        w4.x = fmaf(d0a, s0j[0], W_C * acc[a][0]);
        w4.y = fmaf(d0a, s0j[1], W_C * acc[a][1]);
        w4.z = fmaf(d0a, s0j[2], W_C * acc[a][2]);
        w4.w = fmaf(d0a, s0j[3], W_C * acc[a][3]);
        *(float4*)&P[(i0 + a)*PS + j0] = w4;            // Pn, no Q (ref: Pxz/Pz use Q-less)
      }
    } else if (grp == 4) {
      if (lane < NO) {
        float z = 0.f;
        for (int jj = 0; jj < NS; ++jj) z = fmaf(sHT[jj*HTS + lane], sxp[jj], z);
        sinn[lane] = Yg[sbase*NO + lane] - z;
      }
    }
    __syncthreads();

    // ================= T = H @ Pn (waves 0-1; T[m][:] == Pxz[:,m]) =========
    if (tid < 128) {
      const int m0 = (tid >> 4) << 2;
      const int c0 = (tid & 15) << 2;
      float acc[4][4];
      #pragma unroll
      for (int a = 0; a < 4; ++a)
        #pragma unroll
        for (int b = 0; b < 4; ++b) acc[a][b] = 0.f;
      for (int jj = 0; jj < NS; jj += 4) {
        float hv[16], pv[16];
        #pragma unroll
        for (int k2 = 0; k2 < 4; ++k2) {
          *(float4*)&hv[k2*4] = *(const float4*)&sHT[(jj + k2)*HTS + m0];
          *(float4*)&pv[k2*4] = *(const float4*)&P[(jj + k2)*PS + c0];
        }
        #pragma unroll
        for (int k2 = 0; k2 < 4; ++k2)
          #pragma unroll
          for (int a = 0; a < 4; ++a)
            #pragma unroll
            for (int b = 0; b < 4; ++b)
              acc[a][b] = fmaf(hv[k2*4 + a], pv[k2*4 + b], acc[a][b]);
      }
      #pragma unroll
      for (int a = 0; a < 4; ++a) {
        float4 w4; w4.x = acc[a][0]; w4.y = acc[a][1]; w4.z = acc[a][2]; w4.w = acc[a][3];
        *(float4*)&Tb[(m0 + a)*TS + c0] = w4;
      }
    }
    __syncthreads();

    // ================= Pz = T @ H^T + R (waves 0-1, 2x4 tiles) =============
    if (tid < 128) {
      const int m0 = (tid >> 3) << 1;
      const int n0 = (tid & 7) << 2;
      float4 r0 = *(const float4*)&Rg[m0*NO + n0];
      float4 r1 = *(const float4*)&Rg[(m0 + 1)*NO + n0];
      float acc[2][4] = {{r0.x, r0.y, r0.z, r0.w}, {r1.x, r1.y, r1.z, r1.w}};
      for (int jj = 0; jj < NS; jj += 4) {
        float t0[4], t1[4], hv[16];
        *(float4*)t0 = *(const float4*)&Tb[m0*TS + jj];
        *(float4*)t1 = *(const float4*)&Tb[(m0 + 1)*TS + jj];
        #pragma unroll
        for (int k2 = 0; k2 < 4; ++k2)
          *(float4*)&hv[k2*4] = *(const float4*)&sHT[(jj + k2)*HTS + n0];
        #pragma unroll
        for (int k2 = 0; k2 < 4; ++k2) {
          #pragma unroll
          for (int b = 0; b < 4; ++b) {
            acc[0][b] = fmaf(t0[k2], hv[k2*4 + b], acc[0][b]);
            acc[1][b] = fmaf(t1[k2], hv[k2*4 + b], acc[1][b]);
          }
        }
      }
      #pragma unroll
      for (int a = 0; a < 2; ++a) {
        float4 w4; w4.x = acc[a][0]; w4.y = acc[a][1]; w4.z = acc[a][2]; w4.w = acc[a][3];
        *(float4*)&Pzb[(m0 + a)*GJS + n0] = w4;
      }
    }
    __syncthreads();

    // ================= wave0: in-register Gauss-Jordan inverse of Pz =======
    if (grp == 0) {
      const int c = lane;
      float w[NO];
      #pragma unroll
      for (int r = 0; r < NO; ++r)
        w[r] = (c < NO) ? Pzb[r*GJS + c] : ((c - NO == r) ? 1.f : 0.f);
      #pragma unroll
      for (int p = 0; p < NO; ++p) {
        float piv = __shfl(w[p], p);
        float rp  = 1.0f / piv;
        float wp  = w[p] * rp;
        #pragma unroll
        for (int r = 0; r < NO; ++r) {
          if (r == p) continue;
          float cr = __shfl(w[r], p);
          w[r] = fmaf(-cr, wp, w[r]);
        }
        w[p] = wp;
      }
      if (c >= NO) {
        #pragma unroll
        for (int r = 0; r < NO; ++r) Pzi[(c - NO)*PZS + r] = w[r];
      }
    }
    __syncthreads();

    // ================= K = Pxz @ Pzinv (waves 0-1, 4x4 f4) =================
    if (tid < 128) {
      const int i0 = (tid & 15) << 2;
      const int cb = (tid >> 4) << 2;
      float acc[4][4];
      #pragma unroll
      for (int a = 0; a < 4; ++a)
        #pragma unroll
        for (int b = 0; b < 4; ++b) acc[a][b] = 0.f;
      for (int n = 0; n < NO; n += 4) {
        float tv[16], zv[16];
        #pragma unroll
        for (int k2 = 0; k2 < 4; ++k2)
          *(float4*)&tv[k2*4] = *(const float4*)&Tb[(n + k2)*TS + i0];   // Pxz[i0..][n+k2]
        #pragma unroll
        for (int b = 0; b < 4; ++b)
          *(float4*)&zv[b*4] = *(const float4*)&Pzi[(cb + b)*PZS + n];   // Pzinv[n..n+3][cb+b]
        #pragma unroll
        for (int k2 = 0; k2 < 4; ++k2)
          #pragma unroll
          for (int a = 0; a < 4; ++a)
            #pragma unroll
            for (int b = 0; b < 4; ++b)
              acc[a][b] = fmaf(tv[k2*4 + a], zv[b*4 + k2], acc[a][b]);
      }
      #pragma unroll
      for (int a = 0; a < 4; ++a) {
        float4 w4; w4.x = acc[a][0]; w4.y = acc[a][1]; w4.z = acc[a][2]; w4.w = acc[a][3];
        *(float4*)&Km[(i0 + a)*KS + cb] = w4;
      }
    }
    __syncthreads();

    // ====== fused: M = K@Pxz^T, P_new = (Pn+Q)-Msym, scaled P + outP =======
    //        (lower-triangle 4x4 tiles + mirror writes); wave7: x_new ========
    if (tid < 136) {
      int r = (int)((sqrtf(8.f*(float)tid + 1.f) - 1.f) * 0.5f);
      while ((r + 1)*(r + 2)/2 <= tid) ++r;
      while (r*(r + 1)/2 > tid) --r;
      const int c2 = tid - ((r*(r + 1)) >> 1);
      const int i0 = r << 2, j0 = c2 << 2;
      const bool diag = (r == c2);
      float acc[4][4];
      #pragma unroll
      for (int a = 0; a < 4; ++a)
        #pragma unroll
        for (int b = 0; b < 4; ++b) acc[a][b] = 0.f;
      for (int m = 0; m < NO; m += 4) {
        float ka[16], tb[16];
        #pragma unroll
        for (int a = 0; a < 4; ++a)
          *(float4*)&ka[a*4] = *(const float4*)&Km[(i0 + a)*KS + m];
        #pragma unroll
        for (int k2 = 0; k2 < 4; ++k2)
          *(float4*)&tb[k2*4] = *(const float4*)&Tb[(m + k2)*TS + j0];   // Pxz[j0..][m+k2]
        #pragma unroll
        for (int k2 = 0; k2 < 4; ++k2)
          #pragma unroll
          for (int a = 0; a < 4; ++a)
            #pragma unroll
            for (int b = 0; b < 4; ++b)
              acc[a][b] = fmaf(ka[a*4 + k2], tb[k2*4 + b], acc[a][b]);
      }
      float vres[4][4];
      #pragma unroll
      for (int a = 0; a < 4; ++a) {
        float4 pv = *(const float4*)&P[(i0 + a)*PS + j0];
        float4 qv = *(const float4*)&Qg[(i0 + a)*64 + j0];
        float pa[4] = {pv.x + qv.x, pv.y + qv.y, pv.z + qv.z, pv.w + qv.w};
        #pragma unroll
        for (int b = 0; b < 4; ++b) {
          float mv = diag ? ((a >= b) ? acc[a][b] : acc[b][a]) : acc[a][b];
          vres[a][b] = pa[b] - mv;
        }
      }
      #pragma unroll
      for (int a = 0; a < 4; ++a) {
        float4 g; g.x = vres[a][0]; g.y = vres[a][1]; g.z = vres[a][2]; g.w = vres[a][3];
        *(float4*)&outP[sbase*(size_t)(NS*NS) + (i0 + a)*64 + j0] = g;
        float4 sres;
        sres.x = fmaf(vres[a][0], 63.f, (diag && a == 0) ? DEPS : 0.f);
        sres.y = fmaf(vres[a][1], 63.f, (diag && a == 1) ? DEPS : 0.f);
        sres.z = fmaf(vres[a][2], 63.f, (diag && a == 2) ? DEPS : 0.f);
        sres.w = fmaf(vres[a][3], 63.f, (diag && a == 3) ? DEPS : 0.f);
        *(float4*)&P[(i0 + a)*PS + j0] = sres;
      }
      if (!diag) {
        #pragma unroll
        for (int b = 0; b < 4; ++b) {
          float4 g; g.x = vres[0][b]; g.y = vres[1][b]; g.z = vres[2][b]; g.w = vres[3][b];
          *(float4*)&outP[sbase*(size_t)(NS*NS) + (j0 + b)*64 + i0] = g;
          float4 s2; s2.x = g.x*63.f; s2.y = g.y*63.f; s2.z = g.z*63.f; s2.w = g.w*63.f;
          *(float4*)&P[(j0 + b)*PS + i0] = s2;
        }
      }
    } else if (tid >= 448) {
      const int i = tid - 448;
      float xn = sxp[i];
      #pragma unroll
      for (int mc = 0; mc < NO; mc += 4) {
        float4 kv = *(const float4*)&Km[i*KS + mc];
        float4 iv = *(const float4*)&sinn[mc];
        xn = fmaf(kv.x, iv.x, xn);
        xn = fmaf(kv.y, iv.y, xn);
        xn = fmaf(kv.z, iv.z, xn);
        xn = fmaf(kv.w, iv.w, xn);
      }
      sx[i] = xn;
      outX[sbase*NS + i] = xn;
      float dd = xn - Xg[sbase*NS + i];
      errAcc = fmaf(dd, dd, errAcc);
    }
    __syncthreads();
  }

  // ---- per-trajectory squared-error total (err lives on wave7)
  if (grp == 7) {
    float v = errAcc;
    for (int off = 32; off > 0; off >>= 1) v += __shfl_down(v, off);
    if (lane == 0) wsPart[traj] = v;
  }
}

__global__ __launch_bounds__(128)
void mse_reduce(const float* __restrict__ part, float* __restrict__ outS)
{
  __shared__ float sbuf[128];
  int tid = threadIdx.x;
  sbuf[tid] = part[tid];
  __syncthreads();
  if (tid < 64) {
    float v = sbuf[tid] + sbuf[tid + 64];
    for (int off = 32; off > 0; off >>= 1) v += __shfl_down(v, off);
    if (tid == 0) {
      float m = v / (128.f * 250.f * 64.f);
      outS[0] = m;
      outS[1] = 10.f * log10f(m);
    }
  }
}

extern "C" void kernel_launch(void* const* d_in, const int* in_sizes, int n_in,
                              void* d_out, int out_size, void* d_ws, size_t ws_size,
                              hipStream_t stream) {
  const float* Xg = (const float*)d_in[0];
  const float* Yg = (const float*)d_in[1];
  const float* Fg = (const float*)d_in[2];
  const float* Hg = (const float*)d_in[3];
  const float* Qg = (const float*)d_in[4];
  const float* Rg = (const float*)d_in[5];

  float* outX = (float*)d_out;                                   // 128*250*64
  float* outP = outX + (size_t)NTRAJ*TSTEPS*NS;                  // 128*250*64*64
  float* outS = outP + (size_t)NTRAJ*TSTEPS*NS*NS;               // 2 scalars
  float* wsP  = (float*)d_ws;                                    // 128 partials

  hipLaunchKernelGGL(ukf_main, dim3(NTRAJ), dim3(BLK), 0, stream,
                     Xg, Yg, Fg, Hg, Qg, Rg, outX, outP, wsP);
  hipLaunchKernelGGL(mse_reduce, dim3(1), dim3(128), 0, stream, wsP, outS);
}